// Round 1
// baseline (596.678 us; speedup 1.0000x reference)
//
#include <hip/hip_runtime.h>
#include <stdint.h>

#define RMAX   16
#define NCLS   80
#define NCH    144       // 4*RMAX + NCLS
#define ATOT   8400      // 80*80 + 40*40 + 20*20
#define KDET   300
#define NBATCH 64
#define CONF_T 0.25f
#define IMG_F  640.0f

// Map float -> uint32 such that larger float => SMALLER key (descending order),
// total order matching IEEE-754 ordering of finite floats.
__device__ __forceinline__ uint32_t desc_key(float f) {
    uint32_t u = __float_as_uint(f);
    uint32_t m = (u & 0x80000000u) ? ~u : (u | 0x80000000u); // ascending map
    return ~m;                                               // descending
}

// One thread = 4 consecutive pixels (float4 loads, 16B/lane).
__global__ __launch_bounds__(256) void decode_kernel(
    const float* __restrict__ p, int H, int W, int ancBase, float strideS,
    float4* __restrict__ boxes, float4* __restrict__ scoreV,
    float4* __restrict__ clsV, uint4* __restrict__ ordV)
{
    const int HW = H * W;
    const int quads = HW >> 2;
    const int q = blockIdx.x * 256 + threadIdx.x;
    if (q >= quads) return;
    const int b = blockIdx.y;
    const int pix = q << 2;               // W % 4 == 0, so all 4 pixels share a row
    const int y = pix / W;
    const int x = pix - y * W;
    const float* base = p + (size_t)b * NCH * HW + pix;

    // --- DFL: 4 sides x softmax-expectation over 16 regs ---
    float dist[4][4];
#pragma unroll
    for (int j = 0; j < 4; ++j) {
        float v[16][4];
#pragma unroll
        for (int i = 0; i < 16; ++i) {
            float4 t = *(const float4*)(base + (size_t)(j * 16 + i) * HW);
            v[i][0] = t.x; v[i][1] = t.y; v[i][2] = t.z; v[i][3] = t.w;
        }
#pragma unroll
        for (int k = 0; k < 4; ++k) {
            float m = v[0][k];
#pragma unroll
            for (int i = 1; i < 16; ++i) m = fmaxf(m, v[i][k]);
            float s = 0.f, wsum = 0.f;
#pragma unroll
            for (int i = 0; i < 16; ++i) {
                float e = expf(v[i][k] - m);
                s += e; wsum += e * (float)i;
            }
            dist[j][k] = wsum / s;
        }
    }

    // --- classes: running max + first-argmax (matches jnp.argmax) ---
    float ml[4] = {-3.402823466e38f, -3.402823466e38f, -3.402823466e38f, -3.402823466e38f};
    int am[4] = {0, 0, 0, 0};
#pragma unroll 4
    for (int c = 0; c < NCLS; ++c) {
        float4 t = *(const float4*)(base + (size_t)(64 + c) * HW);
        if (t.x > ml[0]) { ml[0] = t.x; am[0] = c; }
        if (t.y > ml[1]) { ml[1] = t.y; am[1] = c; }
        if (t.z > ml[2]) { ml[2] = t.z; am[2] = c; }
        if (t.w > ml[3]) { ml[3] = t.w; am[3] = c; }
    }

    const int aBase = ancBase + pix;
    const size_t gi = (size_t)b * ATOT + aBase;   // divisible by 4
    float scv[4], clv[4]; uint32_t odv[4];
#pragma unroll
    for (int k = 0; k < 4; ++k) {
        float ax = (float)(x + k) + 0.5f;
        float ay = (float)y + 0.5f;
        float4 bx;
        bx.x = (ax - dist[0][k]) * strideS;
        bx.y = (ay - dist[1][k]) * strideS;
        bx.z = (ax + dist[2][k]) * strideS;
        bx.w = (ay + dist[3][k]) * strideS;
        boxes[gi + k] = bx;
        float sc = 1.0f / (1.0f + expf(-ml[k]));
        scv[k] = sc;
        clv[k] = (float)am[k];
        // ranking key: raw max logit (exact), masked anchors sort last (key 0xFFFFFFFF,
        // all equal -1.0 in ref -> index-ascending, which our (key,index) order preserves)
        odv[k] = (sc >= CONF_T) ? desc_key(ml[k]) : 0xFFFFFFFFu;
    }
    scoreV[gi >> 2] = make_float4(scv[0], scv[1], scv[2], scv[3]);
    clsV[gi >> 2]   = make_float4(clv[0], clv[1], clv[2], clv[3]);
    ordV[gi >> 2]   = make_uint4(odv[0], odv[1], odv[2], odv[3]);
}

__device__ __forceinline__ int block_reduce_sum(int v, volatile int* red) {
    const int tid = threadIdx.x;
    red[tid] = v;
    __syncthreads();
    for (int s = 128; s > 0; s >>= 1) {
        if (tid < s) red[tid] += red[tid + s];
        __syncthreads();
    }
    int r = red[0];
    __syncthreads();
    return r;
}

// One block per batch. Exact top-300 by (desc_key, anchor_index) ascending.
__global__ __launch_bounds__(256) void topk_kernel(
    const float4* __restrict__ boxes, const float* __restrict__ score,
    const float* __restrict__ clsArr, const uint32_t* __restrict__ ordArr,
    float* __restrict__ out)
{
    __shared__ uint32_t sk[ATOT];            // 33.6 KB
    __shared__ int red[256];
    __shared__ unsigned long long win[KDET];
    __shared__ int cnt, ndet;
    const int tid = threadIdx.x;
    const int b = blockIdx.x;

    for (int i = tid; i < ATOT; i += 256) sk[i] = ordArr[(size_t)b * ATOT + i];
    if (tid == 0) { cnt = 0; ndet = 0; }
    __syncthreads();

    // 1) binary search: T = smallest key value with count(sk <= T) >= KDET
    uint32_t lo = 0u, hi = 0xFFFFFFFFu;
    while (lo < hi) {
        uint32_t mid = lo + ((hi - lo) >> 1);
        int c = 0;
        for (int i = tid; i < ATOT; i += 256) c += (sk[i] <= mid) ? 1 : 0;
        c = block_reduce_sum(c, red);
        if (c >= KDET) hi = mid; else lo = mid + 1;
    }
    const uint32_t T = lo;

    // 2) c_less = count(sk < T); need m more winners from the sk==T group
    int c = 0;
    for (int i = tid; i < ATOT; i += 256) c += (sk[i] < T) ? 1 : 0;
    const int c_less = block_reduce_sum(c, red);
    const int m = KDET - c_less;             // >= 1

    // 3) among sk==T, take the m smallest anchor indices (ties in ref are
    //    equal scores -> stable/lowest-index-first, same as our order)
    int ilo = 0, ihi = ATOT - 1;
    while (ilo < ihi) {
        int mid = (ilo + ihi) >> 1;
        int cc = 0;
        for (int i = tid; i <= mid; i += 256) cc += (sk[i] == T) ? 1 : 0;
        cc = block_reduce_sum(cc, red);
        if (cc >= m) ihi = mid; else ilo = mid + 1;
    }
    const int idx_cut = ilo;

    // 4) collect exactly KDET winners (unordered)
    for (int i = tid; i < ATOT; i += 256) {
        uint32_t k = sk[i];
        if (k < T || (k == T && i <= idx_cut)) {
            int p = atomicAdd(&cnt, 1);
            win[p] = ((unsigned long long)k << 32) | (uint32_t)i;
        }
    }
    __syncthreads();

    // 5) rank by counting (keys unique: index embedded), gather + write rows
    int local_nd = 0;
    for (int w = tid; w < KDET; w += 256) {
        const unsigned long long k = win[w];
        int r = 0;
        for (int v = 0; v < KDET; ++v) r += (win[v] < k) ? 1 : 0;
        const uint32_t a = (uint32_t)(k & 0xFFFFFFFFu);
        const size_t gi = (size_t)b * ATOT + a;
        const float4 bx = boxes[gi];
        const float sc = fmaxf(score[gi], 0.0f);
        const float cl = clsArr[gi];
        float* row = out + ((size_t)b * KDET + r) * 6;
        row[0] = fminf(fmaxf(bx.x, 0.0f), IMG_F);
        row[1] = fminf(fmaxf(bx.y, 0.0f), IMG_F);
        row[2] = fminf(fmaxf(bx.z, 0.0f), IMG_F);
        row[3] = fminf(fmaxf(bx.w, 0.0f), IMG_F);
        row[4] = sc;
        row[5] = cl;
        if (sc >= CONF_T) ++local_nd;
    }
    atomicAdd(&ndet, local_nd);
    __syncthreads();
    if (tid == 0) out[(size_t)NBATCH * KDET * 6 + b] = (float)ndet;
}

extern "C" void kernel_launch(void* const* d_in, const int* in_sizes, int n_in,
                              void* d_out, int out_size, void* d_ws, size_t ws_size,
                              hipStream_t stream) {
    const float* p8  = (const float*)d_in[0];
    const float* p16 = (const float*)d_in[1];
    const float* p32 = (const float*)d_in[2];

    // workspace layout (needs ~15.1 MB)
    char* ws = (char*)d_ws;
    const size_t nBA = (size_t)NBATCH * ATOT;          // 537600
    float4*   boxes  = (float4*)ws;                    // 16 B * nBA = 8,601,600
    float*    score  = (float*)(ws + 16 * nBA);        //  4 B * nBA
    float*    cls    = (float*)(ws + 20 * nBA);
    uint32_t* ord    = (uint32_t*)(ws + 24 * nBA);

    dim3 blk(256);
    // level 8: HW=6400 -> 1600 quads -> 7 blocks; level 16: 400 quads -> 2; level 32: 100 -> 1
    decode_kernel<<<dim3(7, NBATCH), blk, 0, stream>>>(p8,  80, 80,    0,  8.f,
        boxes, (float4*)score, (float4*)cls, (uint4*)ord);
    decode_kernel<<<dim3(2, NBATCH), blk, 0, stream>>>(p16, 40, 40, 6400, 16.f,
        boxes, (float4*)score, (float4*)cls, (uint4*)ord);
    decode_kernel<<<dim3(1, NBATCH), blk, 0, stream>>>(p32, 20, 20, 8000, 32.f,
        boxes, (float4*)score, (float4*)cls, (uint4*)ord);

    topk_kernel<<<dim3(NBATCH), blk, 0, stream>>>(boxes, score, cls, ord, (float*)d_out);
}

// Round 2
// 430.260 us; speedup vs baseline: 1.3868x; 1.3868x over previous
//
#include <hip/hip_runtime.h>
#include <stdint.h>

#define RMAX   16
#define NCLS   80
#define NCH    144       // 4*RMAX + NCLS
#define A8     6400
#define ATOT   8400      // 6400 + 1600 + 400
#define KDET   300
#define NBATCH 64
#define CONF_T 0.25f
#define IMG_F  640.0f

// Map float -> uint32 such that larger float => SMALLER key (descending order),
// total order matching IEEE-754 ordering of finite floats.
__device__ __forceinline__ uint32_t desc_key(float f) {
    uint32_t u = __float_as_uint(f);
    uint32_t m = (u & 0x80000000u) ? ~u : (u | 0x80000000u); // ascending map
    return ~m;                                               // descending
}

// Thread-per-anchor decode, all three pyramid levels in one launch.
// Wave reads 64 consecutive floats per channel (256 B, fully coalesced).
__global__ __launch_bounds__(256, 6) void decode_kernel(
    const float* __restrict__ p8, const float* __restrict__ p16,
    const float* __restrict__ p32,
    float4* __restrict__ boxes, float* __restrict__ score,
    float* __restrict__ cls, uint32_t* __restrict__ ord)
{
    const int a = blockIdx.x * 256 + threadIdx.x;
    if (a >= ATOT) return;
    const int b = blockIdx.y;

    const float* p; int HW, W, pix; float strideS;
    if (a < A8)        { p = p8;  HW = 6400; W = 80; pix = a;        strideS = 8.f;  }
    else if (a < 8000) { p = p16; HW = 1600; W = 40; pix = a - 6400; strideS = 16.f; }
    else               { p = p32; HW = 400;  W = 20; pix = a - 8000; strideS = 32.f; }

    const int y = pix / W;
    const int x = pix - y * W;
    const float* base = p + (size_t)b * NCH * HW + pix;

    // --- DFL: 4 sides x softmax-expectation over 16 regs ---
    float dist[4];
#pragma unroll
    for (int j = 0; j < 4; ++j) {
        float v[16];
#pragma unroll
        for (int i = 0; i < 16; ++i) v[i] = base[(size_t)(j * 16 + i) * HW];
        float mx = v[0];
#pragma unroll
        for (int i = 1; i < 16; ++i) mx = fmaxf(mx, v[i]);
        float s = 0.f, wsum = 0.f;
#pragma unroll
        for (int i = 0; i < 16; ++i) {
            float e = __expf(v[i] - mx);
            s += e; wsum += e * (float)i;
        }
        dist[j] = wsum / s;
    }

    // --- classes: running max + first-argmax (matches jnp.argmax) ---
    float ml = -3.402823466e38f; int am = 0;
#pragma unroll 8
    for (int c = 0; c < NCLS; ++c) {
        float t = base[(size_t)(64 + c) * HW];
        if (t > ml) { ml = t; am = c; }
    }

    const size_t gi = (size_t)b * ATOT + a;
    const float ax = (float)x + 0.5f, ay = (float)y + 0.5f;
    float4 bx;
    bx.x = (ax - dist[0]) * strideS;
    bx.y = (ay - dist[1]) * strideS;
    bx.z = (ax + dist[2]) * strideS;
    bx.w = (ay + dist[3]) * strideS;
    boxes[gi] = bx;
    const float sc = 1.0f / (1.0f + __expf(-ml));
    score[gi] = sc;
    cls[gi] = (float)am;
    // ranking key: raw max logit (exact input data), masked anchors sort last
    ord[gi] = (sc >= CONF_T) ? desc_key(ml) : 0xFFFFFFFFu;
}

__device__ __forceinline__ int block_reduce_sum(int v, volatile int* red) {
    const int tid = threadIdx.x;
    red[tid] = v;
    __syncthreads();
    for (int s = 128; s > 0; s >>= 1) {
        if (tid < s) red[tid] += red[tid + s];
        __syncthreads();
    }
    int r = red[0];
    __syncthreads();
    return r;
}

// One block per batch. Exact top-300 by (desc_key, anchor_index) ascending,
// via 4-pass 8-bit radix select (replaces 32-iteration binary search).
__global__ __launch_bounds__(256) void topk_kernel(
    const float4* __restrict__ boxes, const float* __restrict__ score,
    const float* __restrict__ clsArr, const uint32_t* __restrict__ ordArr,
    float* __restrict__ out)
{
    __shared__ uint32_t sk[ATOT];            // 33.6 KB
    __shared__ int hist[256];
    __shared__ int scanb[256];
    __shared__ int red[256];
    __shared__ unsigned long long win[KDET];
    __shared__ int eqIdx[64];
    __shared__ int s_digit, s_m, eqCnt, cnt, ndet;
    const int tid = threadIdx.x;
    const int b = blockIdx.x;

    for (int i = tid; i < ATOT; i += 256) sk[i] = ordArr[(size_t)b * ATOT + i];
    if (tid == 0) { eqCnt = 0; cnt = 0; ndet = 0; }
    __syncthreads();

    // Radix select: after 4 passes prefix==T (the KDET-th smallest key value)
    // and m == number of winners to take from the sk==T group.
    uint32_t prefix = 0; int m = KDET;
#pragma unroll
    for (int pass = 3; pass >= 0; --pass) {
        const uint32_t hiMask = (pass == 3) ? 0u : (0xFFFFFFFFu << ((pass + 1) * 8));
        const int sh = pass * 8;
        hist[tid] = 0;
        __syncthreads();
        for (int i = tid; i < ATOT; i += 256) {
            const uint32_t k = sk[i];
            if (((k ^ prefix) & hiMask) == 0)
                atomicAdd(&hist[(k >> sh) & 0xFF], 1);
        }
        __syncthreads();
        scanb[tid] = hist[tid];
        __syncthreads();
        for (int off = 1; off < 256; off <<= 1) {     // inclusive Hillis-Steele scan
            const int t = (tid >= off) ? scanb[tid - off] : 0;
            __syncthreads();
            scanb[tid] += t;
            __syncthreads();
        }
        const int prev = (tid == 0) ? 0 : scanb[tid - 1];
        if (scanb[tid] >= m && prev < m) { s_digit = tid; s_m = m - prev; }
        __syncthreads();
        prefix |= ((uint32_t)s_digit) << sh;
        m = s_m;
    }
    const uint32_t T = prefix;

    // Gather the sk==T group (tiny in practice; fallback handles overflow)
    for (int i = tid; i < ATOT; i += 256) {
        if (sk[i] == T) { const int p = atomicAdd(&eqCnt, 1); if (p < 64) eqIdx[p] = i; }
    }
    __syncthreads();
    const int ec = eqCnt;

    // Collect winners: all k < T ...
    for (int i = tid; i < ATOT; i += 256) {
        const uint32_t k = sk[i];
        if (k < T) { const int p = atomicAdd(&cnt, 1); win[p] = ((unsigned long long)k << 32) | (uint32_t)i; }
    }
    // ... plus the m smallest-index among k == T (ref tie-break: stable/low index)
    if (ec <= 64) {
        if (tid < ec) {
            const int my = eqIdx[tid]; int r = 0;
            for (int v2 = 0; v2 < ec; ++v2) r += (eqIdx[v2] < my) ? 1 : 0;
            if (r < m) { const int p = atomicAdd(&cnt, 1); win[p] = ((unsigned long long)T << 32) | (uint32_t)my; }
        }
    } else {
        // degenerate (mass ties, e.g. >300 masked): exact index-cut binary search
        int ilo = 0, ihi = ATOT - 1;
        while (ilo < ihi) {
            const int mid = (ilo + ihi) >> 1;
            int cc = 0;
            for (int i = tid; i <= mid; i += 256) cc += (sk[i] == T) ? 1 : 0;
            cc = block_reduce_sum(cc, red);
            if (cc >= m) ihi = mid; else ilo = mid + 1;
        }
        for (int i = tid; i <= ilo; i += 256) {
            if (sk[i] == T) { const int p = atomicAdd(&cnt, 1); win[p] = ((unsigned long long)T << 32) | (uint32_t)i; }
        }
    }
    __syncthreads();

    // Rank by counting (keys unique: index embedded), gather + write rows
    int local_nd = 0;
    for (int w = tid; w < KDET; w += 256) {
        const unsigned long long k = win[w];
        int r = 0;
        for (int v2 = 0; v2 < KDET; ++v2) r += (win[v2] < k) ? 1 : 0;
        const uint32_t a = (uint32_t)(k & 0xFFFFFFFFu);
        const size_t gi = (size_t)b * ATOT + a;
        const float4 bx = boxes[gi];
        const float sc = fmaxf(score[gi], 0.0f);
        const float cl = clsArr[gi];
        float* row = out + ((size_t)b * KDET + r) * 6;
        row[0] = fminf(fmaxf(bx.x, 0.0f), IMG_F);
        row[1] = fminf(fmaxf(bx.y, 0.0f), IMG_F);
        row[2] = fminf(fmaxf(bx.z, 0.0f), IMG_F);
        row[3] = fminf(fmaxf(bx.w, 0.0f), IMG_F);
        row[4] = sc;
        row[5] = cl;
        if (sc >= CONF_T) ++local_nd;
    }
    atomicAdd(&ndet, local_nd);
    __syncthreads();
    if (tid == 0) out[(size_t)NBATCH * KDET * 6 + b] = (float)ndet;
}

extern "C" void kernel_launch(void* const* d_in, const int* in_sizes, int n_in,
                              void* d_out, int out_size, void* d_ws, size_t ws_size,
                              hipStream_t stream) {
    const float* p8  = (const float*)d_in[0];
    const float* p16 = (const float*)d_in[1];
    const float* p32 = (const float*)d_in[2];

    // workspace layout (~15.1 MB)
    char* ws = (char*)d_ws;
    const size_t nBA = (size_t)NBATCH * ATOT;          // 537600
    float4*   boxes  = (float4*)ws;                    // 16 B * nBA
    float*    score  = (float*)(ws + 16 * nBA);        //  4 B * nBA
    float*    cls    = (float*)(ws + 20 * nBA);
    uint32_t* ord    = (uint32_t*)(ws + 24 * nBA);

    // 8400 anchors / 256 = 33 blocks per batch, all levels in one launch
    decode_kernel<<<dim3(33, NBATCH), dim3(256), 0, stream>>>(
        p8, p16, p32, boxes, score, cls, ord);

    topk_kernel<<<dim3(NBATCH), dim3(256), 0, stream>>>(
        boxes, score, cls, ord, (float*)d_out);
}

// Round 3
// 406.704 us; speedup vs baseline: 1.4671x; 1.0579x over previous
//
#include <hip/hip_runtime.h>
#include <stdint.h>

#define RMAX   16
#define NCLS   80
#define NCH    144       // 4*RMAX + NCLS
#define ATOT   8400      // 6400 + 1600 + 400
#define KDET   300
#define NBATCH 64
#define CONF_T 0.25f
#define IMG_F  640.0f

// Map float -> uint32 such that larger float => SMALLER key (descending order),
// total order matching IEEE-754 ordering of finite floats.
__device__ __forceinline__ uint32_t desc_key(float f) {
    uint32_t u = __float_as_uint(f);
    uint32_t m = (u & 0x80000000u) ? ~u : (u | 0x80000000u); // ascending map
    return ~m;                                               // descending
}

// Block-cooperative decode: 64 anchors/block, all 144 channels staged to LDS
// via global_load_lds (16 B/lane, 9 wave-instructions in flight = 9 KB/wave).
// Grid: (132, NBATCH). Blocks 0..99 -> p8, 100..124 -> p16, 125..131 -> p32.
__global__ __launch_bounds__(256) void decode_kernel(
    const float* __restrict__ p8, const float* __restrict__ p16,
    const float* __restrict__ p32,
    float4* __restrict__ boxes, float* __restrict__ score,
    float* __restrict__ cls, uint32_t* __restrict__ ord)
{
    __shared__ float tile[NCH * 64];      // 36,864 B: tile[ch*64 + anchor]
    __shared__ float distS[4 * 64];
    __shared__ float mlS[4 * 64];
    __shared__ int   amS[4 * 64];

    const int bx = blockIdx.x, b = blockIdx.y;
    const float* p; int HW, W, local, abase, nanc; float strideS;
    if (bx < 100)      { p = p8;  HW = 6400; W = 80; local = bx * 64;         abase = local;        nanc = 64; strideS = 8.f; }
    else if (bx < 125) { p = p16; HW = 1600; W = 40; local = (bx - 100) * 64; abase = 6400 + local; nanc = 64; strideS = 16.f; }
    else               { p = p32; HW = 400;  W = 20; local = (bx - 125) * 64; abase = 8000 + local;
                         nanc = (400 - local >= 64) ? 64 : (400 - local);     strideS = 32.f; }

    const int t = threadIdx.x, w = t >> 6, lane = t & 63;
    const int vec = lane & 15, chIn = lane >> 4;     // lane = chIn*16 + vec
    const int nvec = nanc >> 2;                      // 16 (full) or 4 (tail)
    const float* gb = p + (size_t)b * NCH * HW + local;

    // Stage: chunk c covers channels [4c, 4c+4); wave w owns chunks c % 4 == w.
    // Lane l of the wave writes LDS at tile[c*256] + l*16 B == tile[ch*64 + vec*4]
    // (wave-uniform base + lane*16 semantics), which is exactly channel-major order.
#pragma unroll
    for (int k = 0; k < 9; ++k) {
        const int c = w + k * 4;
        if (vec < nvec) {
            const float* g = gb + (size_t)(c * 4 + chIn) * HW + vec * 4;
            __builtin_amdgcn_global_load_lds(
                (const __attribute__((address_space(1))) void*)g,
                (__attribute__((address_space(3))) void*)(tile + c * 256),
                16, 0, 0);
        }
    }
    __syncthreads();

    if (lane < nanc) {
        // DFL: wave w handles side j = w for its anchor (lane-consecutive LDS reads)
        float v[16];
#pragma unroll
        for (int i = 0; i < 16; ++i) v[i] = tile[(w * 16 + i) * 64 + lane];
        float mx = v[0];
#pragma unroll
        for (int i = 1; i < 16; ++i) mx = fmaxf(mx, v[i]);
        float s = 0.f, wsum = 0.f;
#pragma unroll
        for (int i = 0; i < 16; ++i) {
            float e = __expf(v[i] - mx);
            s += e; wsum += e * (float)i;
        }
        distS[w * 64 + lane] = wsum / s;

        // classes [20w, 20w+20): partial running max + first-argmax
        float ml = -3.402823466e38f; int am = 0;
#pragma unroll
        for (int c2 = 0; c2 < 20; ++c2) {
            const float tv = tile[(64 + w * 20 + c2) * 64 + lane];
            if (tv > ml) { ml = tv; am = w * 20 + c2; }
        }
        mlS[w * 64 + lane] = ml; amS[w * 64 + lane] = am;
    }
    __syncthreads();

    // wave 0: merge partials in ascending class-range order (preserves
    // first-argmax semantics), assemble outputs, coalesced writes.
    if (w == 0 && lane < nanc) {
        float ml = mlS[lane]; int am = amS[lane];
#pragma unroll
        for (int ww = 1; ww < 4; ++ww) {
            const float m2 = mlS[ww * 64 + lane];
            if (m2 > ml) { ml = m2; am = amS[ww * 64 + lane]; }
        }
        const int pix = local + lane;
        const int y = pix / W, x = pix - y * W;
        const float ax = (float)x + 0.5f, ay = (float)y + 0.5f;
        float4 bb;
        bb.x = (ax - distS[lane])       * strideS;
        bb.y = (ay - distS[64 + lane])  * strideS;
        bb.z = (ax + distS[128 + lane]) * strideS;
        bb.w = (ay + distS[192 + lane]) * strideS;
        const size_t gi = (size_t)b * ATOT + abase + lane;
        boxes[gi] = bb;
        const float sc = 1.0f / (1.0f + __expf(-ml));
        score[gi] = sc;
        cls[gi] = (float)am;
        // ranking key: raw max logit (exact input data), masked anchors sort last
        ord[gi] = (sc >= CONF_T) ? desc_key(ml) : 0xFFFFFFFFu;
    }
}

__device__ __forceinline__ int wave_sum(int v) {
#pragma unroll
    for (int o = 32; o > 0; o >>= 1) v += __shfl_down(v, o, 64);
    return v;   // valid in lane 0
}

// One block per batch. Exact top-300 by (desc_key, anchor_index) ascending.
// Binary search on key value; count via wave shfl-reduce + 4-entry LDS combine
// (1 barrier/iter, no contended atomics -- the R2 radix histogram serialized
// ~8400 atomicAdds onto 1-2 bins because all keys concentrate).
__global__ __launch_bounds__(256) void topk_kernel(
    const float4* __restrict__ boxes, const float* __restrict__ score,
    const float* __restrict__ clsArr, const uint32_t* __restrict__ ordArr,
    float* __restrict__ out)
{
    __shared__ uint32_t sk[ATOT];            // 33.6 KB
    __shared__ int red4[2][4];
    __shared__ unsigned long long win[KDET];
    __shared__ int eqIdx[64];
    __shared__ int eqCnt, cnt, ndet;
    const int tid = threadIdx.x;
    const int w = tid >> 6, lane = tid & 63;
    const int b = blockIdx.x;

    for (int i = tid; i < ATOT; i += 256) sk[i] = ordArr[(size_t)b * ATOT + i];
    if (tid == 0) { eqCnt = 0; cnt = 0; ndet = 0; }
    __syncthreads();

    // 1) binary search: T = smallest key value with count(sk <= T) >= KDET
    uint32_t lo = 0u, hi = 0xFFFFFFFFu;
    int parity = 0;
    while (lo < hi) {
        const uint32_t mid = lo + ((hi - lo) >> 1);
        int c = 0;
        for (int i = tid; i < ATOT; i += 256) c += (sk[i] <= mid) ? 1 : 0;
        c = wave_sum(c);
        if (lane == 0) red4[parity][w] = c;
        __syncthreads();
        c = red4[parity][0] + red4[parity][1] + red4[parity][2] + red4[parity][3];
        parity ^= 1;
        if (c >= KDET) hi = mid; else lo = mid + 1;
    }
    const uint32_t T = lo;

    // 2) m = winners still needed from the sk==T group
    int c = 0;
    for (int i = tid; i < ATOT; i += 256) c += (sk[i] < T) ? 1 : 0;
    c = wave_sum(c);
    if (lane == 0) red4[parity][w] = c;
    __syncthreads();
    const int c_less = red4[parity][0] + red4[parity][1] + red4[parity][2] + red4[parity][3];
    parity ^= 1;
    const int m = KDET - c_less;             // >= 1

    // 3) gather the sk==T group (tiny in practice; fallback for mass ties)
    for (int i = tid; i < ATOT; i += 256) {
        if (sk[i] == T) { const int p2 = atomicAdd(&eqCnt, 1); if (p2 < 64) eqIdx[p2] = i; }
    }
    __syncthreads();
    const int ec = eqCnt;

    // 4) collect winners: all k < T (~300 atomics total, no contention storm)
    for (int i = tid; i < ATOT; i += 256) {
        const uint32_t k = sk[i];
        if (k < T) { const int p2 = atomicAdd(&cnt, 1); win[p2] = ((unsigned long long)k << 32) | (uint32_t)i; }
    }
    // ... plus the m smallest-index among k == T (ref tie-break: stable/low index)
    if (ec <= 64) {
        if (tid < ec) {
            const int my = eqIdx[tid]; int r = 0;
            for (int v2 = 0; v2 < ec; ++v2) r += (eqIdx[v2] < my) ? 1 : 0;
            if (r < m) { const int p2 = atomicAdd(&cnt, 1); win[p2] = ((unsigned long long)T << 32) | (uint32_t)my; }
        }
    } else {
        // degenerate (>64 exact ties): exact index-cut binary search, cheap reduce
        int ilo = 0, ihi = ATOT - 1;
        while (ilo < ihi) {
            const int mid = (ilo + ihi) >> 1;
            int cc = 0;
            for (int i = tid; i <= mid; i += 256) cc += (sk[i] == T) ? 1 : 0;
            cc = wave_sum(cc);
            if (lane == 0) red4[parity][w] = cc;
            __syncthreads();
            cc = red4[parity][0] + red4[parity][1] + red4[parity][2] + red4[parity][3];
            parity ^= 1;
            if (cc >= m) ihi = mid; else ilo = mid + 1;
        }
        for (int i = tid; i <= ilo; i += 256) {
            if (sk[i] == T) { const int p2 = atomicAdd(&cnt, 1); win[p2] = ((unsigned long long)T << 32) | (uint32_t)i; }
        }
    }
    __syncthreads();

    // 5) rank by counting (keys unique: index embedded; inner reads broadcast)
    int local_nd = 0;
    for (int ww = tid; ww < KDET; ww += 256) {
        const unsigned long long k = win[ww];
        int r = 0;
        for (int v2 = 0; v2 < KDET; ++v2) r += (win[v2] < k) ? 1 : 0;
        const uint32_t a = (uint32_t)(k & 0xFFFFFFFFu);
        const size_t gi = (size_t)b * ATOT + a;
        const float4 bx = boxes[gi];
        const float sc = fmaxf(score[gi], 0.0f);
        const float cl = clsArr[gi];
        float* row = out + ((size_t)b * KDET + r) * 6;
        row[0] = fminf(fmaxf(bx.x, 0.0f), IMG_F);
        row[1] = fminf(fmaxf(bx.y, 0.0f), IMG_F);
        row[2] = fminf(fmaxf(bx.z, 0.0f), IMG_F);
        row[3] = fminf(fmaxf(bx.w, 0.0f), IMG_F);
        row[4] = sc;
        row[5] = cl;
        if (sc >= CONF_T) ++local_nd;
    }
    atomicAdd(&ndet, local_nd);
    __syncthreads();
    if (tid == 0) out[(size_t)NBATCH * KDET * 6 + b] = (float)ndet;
}

extern "C" void kernel_launch(void* const* d_in, const int* in_sizes, int n_in,
                              void* d_out, int out_size, void* d_ws, size_t ws_size,
                              hipStream_t stream) {
    const float* p8  = (const float*)d_in[0];
    const float* p16 = (const float*)d_in[1];
    const float* p32 = (const float*)d_in[2];

    // workspace layout (~15.1 MB)
    char* ws = (char*)d_ws;
    const size_t nBA = (size_t)NBATCH * ATOT;          // 537600
    float4*   boxes  = (float4*)ws;                    // 16 B * nBA
    float*    score  = (float*)(ws + 16 * nBA);        //  4 B * nBA
    float*    cls    = (float*)(ws + 20 * nBA);
    uint32_t* ord    = (uint32_t*)(ws + 24 * nBA);

    // 100 (p8) + 25 (p16) + 7 (p32, last block 16 anchors) = 132 blocks/batch
    decode_kernel<<<dim3(132, NBATCH), dim3(256), 0, stream>>>(
        p8, p16, p32, boxes, score, cls, ord);

    topk_kernel<<<dim3(NBATCH), dim3(256), 0, stream>>>(
        boxes, score, cls, ord, (float*)d_out);
}